// Round 2
// baseline (40.856 us; speedup 1.0000x reference)
//
#include <hip/hip_runtime.h>
#include <hip/hip_bf16.h>
#include <math.h>

// out[b] = bias + sum_{i,j} W[i,j] * leaky(cf[b,i]*pf[b,j]),  leaky(z)=0.55z+0.45|z|
//        = bias + 0.55 * cf[b]^T W pf[b] + 0.45 * |cf[b]|^T W |pf[b]|
// MFMA path: G = cf @ W, H = |cf| @ W  (bf16 inputs, f32 accum), fused epilogue
// dots against f32 pf and atomicAdds per-batch partials (linear => K-split OK).

constexpr int B = 256, D = 1024;
constexpr int KSPLIT = 8, KCHUNK = D / KSPLIT; // 128
constexpr int NTILES = 32;                      // BN = 32 -> 32 n-tiles

typedef __attribute__((ext_vector_type(8))) short bf16x8;
typedef __attribute__((ext_vector_type(4))) float f32x4;
typedef __attribute__((ext_vector_type(4))) int int32x4;

__device__ __forceinline__ ushort f2bf(float x) {
    __hip_bfloat16 h = __float2bfloat16(x);
    return *reinterpret_cast<ushort*>(&h);
}

// ---------------- prep: Wt bf16 transpose, cf bf16 convert, out=bias ----------------
// blocks [0,256): transpose 64x64 f32 tile of W -> Wt[j][i] bf16
// blocks [256,384): cf f32 -> cfb bf16 (8 elems/thread)
// block 384: out[t] = bias
__global__ __launch_bounds__(256) void opl_prep(
    const float* __restrict__ W, const float* __restrict__ cf,
    const float* __restrict__ bias,
    ushort* __restrict__ Wt, ushort* __restrict__ cfb,
    float* __restrict__ out)
{
    const int blk = blockIdx.x;
    const int t = threadIdx.x;
    if (blk < 256) {
        __shared__ float lds[64][65];
        const int i0 = (blk >> 4) * 64, j0 = (blk & 15) * 64;
        #pragma unroll
        for (int p = 0; p < 4; ++p) {
            const int r = (t >> 4) + p * 16;
            const int c = (t & 15) * 4;
            const float4 v = *reinterpret_cast<const float4*>(&W[(size_t)(i0 + r) * D + j0 + c]);
            lds[r][c + 0] = v.x; lds[r][c + 1] = v.y;
            lds[r][c + 2] = v.z; lds[r][c + 3] = v.w;
        }
        __syncthreads();
        const int jr = t >> 2;        // 0..63 (j within tile)
        const int ib = (t & 3) * 16;  // i sub-block
        bf16x8 v0, v1;
        #pragma unroll
        for (int e = 0; e < 8; ++e) v0[e] = (short)f2bf(lds[ib + e][jr]);
        #pragma unroll
        for (int e = 0; e < 8; ++e) v1[e] = (short)f2bf(lds[ib + 8 + e][jr]);
        ushort* dst = &Wt[(size_t)(j0 + jr) * D + i0 + ib];
        *reinterpret_cast<bf16x8*>(dst) = v0;
        *reinterpret_cast<bf16x8*>(dst + 8) = v1;
    } else if (blk < 384) {
        const size_t base = ((size_t)(blk - 256) * 256 + t) * 8;
        const float4 a = *reinterpret_cast<const float4*>(&cf[base]);
        const float4 b = *reinterpret_cast<const float4*>(&cf[base + 4]);
        bf16x8 v;
        v[0] = (short)f2bf(a.x); v[1] = (short)f2bf(a.y);
        v[2] = (short)f2bf(a.z); v[3] = (short)f2bf(a.w);
        v[4] = (short)f2bf(b.x); v[5] = (short)f2bf(b.y);
        v[6] = (short)f2bf(b.z); v[7] = (short)f2bf(b.w);
        *reinterpret_cast<bf16x8*>(&cfb[base]) = v;
    } else {
        out[t] = bias[0];
    }
}

// ---------------- main MFMA kernel ----------------
// grid = NTILES * KSPLIT = 256 blocks, 4 waves each; wave: 64 b x 32 j, K-chunk 128.
__global__ __launch_bounds__(256) void opl_mfma(
    const ushort* __restrict__ cfb, const ushort* __restrict__ Wt,
    const float* __restrict__ pf, float* __restrict__ out)
{
    const int nt = blockIdx.x & (NTILES - 1);
    const int kc = blockIdx.x >> 5;
    const int nbase = nt * 32, kbase = kc * KCHUNK;
    const int lane = threadIdx.x & 63;
    const int wid = threadIdx.x >> 6;
    const int mwave = wid * 64;
    const int r16 = lane & 15;  // m/n index within fragment
    const int kb = lane >> 4;   // k-block: k = kb*8 + e

    f32x4 accG[4][2] = {};
    f32x4 accH[4][2] = {};

    const ushort* cfp = cfb + (size_t)(mwave + r16) * D + kbase + kb * 8;
    const ushort* wtp = Wt + (size_t)(nbase + r16) * D + kbase + kb * 8;

    #pragma unroll
    for (int ks = 0; ks < KCHUNK / 32; ++ks) {
        bf16x8 a[4], b[2];
        #pragma unroll
        for (int mf = 0; mf < 4; ++mf)
            a[mf] = *reinterpret_cast<const bf16x8*>(cfp + (size_t)mf * 16 * D + ks * 32);
        #pragma unroll
        for (int nf = 0; nf < 2; ++nf)
            b[nf] = *reinterpret_cast<const bf16x8*>(wtp + (size_t)nf * 16 * D + ks * 32);
        #pragma unroll
        for (int mf = 0; mf < 4; ++mf) {
            int32x4 ai = __builtin_bit_cast(int32x4, a[mf]);
            ai &= 0x7fff7fff;  // |bf16| exactly: clear sign bits
            const bf16x8 aa = __builtin_bit_cast(bf16x8, ai);
            #pragma unroll
            for (int nf = 0; nf < 2; ++nf) {
                accG[mf][nf] = __builtin_amdgcn_mfma_f32_16x16x32_bf16(a[mf], b[nf], accG[mf][nf], 0, 0, 0);
                accH[mf][nf] = __builtin_amdgcn_mfma_f32_16x16x32_bf16(aa,    b[nf], accH[mf][nf], 0, 0, 0);
            }
        }
    }

    // epilogue: s[mf][r] = sum over this lane's cols of 0.55 p G + 0.45 |p| H
    float s[4][4];
    #pragma unroll
    for (int mf = 0; mf < 4; ++mf)
        #pragma unroll
        for (int r = 0; r < 4; ++r) s[mf][r] = 0.f;

    #pragma unroll
    for (int mf = 0; mf < 4; ++mf) {
        #pragma unroll
        for (int nf = 0; nf < 2; ++nf) {
            #pragma unroll
            for (int r = 0; r < 4; ++r) {
                const int brow = mwave + mf * 16 + kb * 4 + r;  // C/D: row=(lane>>4)*4+r
                const float p = pf[(size_t)brow * D + nbase + nf * 16 + r16];
                s[mf][r] = fmaf(0.55f * p, accG[mf][nf][r],
                           fmaf(0.45f * fabsf(p), accH[mf][nf][r], s[mf][r]));
            }
        }
    }
    // reduce across the 16 column-lanes (xor masks < 16 stay within each group)
    #pragma unroll
    for (int mf = 0; mf < 4; ++mf) {
        #pragma unroll
        for (int r = 0; r < 4; ++r) {
            float v = s[mf][r];
            v += __shfl_xor(v, 1);
            v += __shfl_xor(v, 2);
            v += __shfl_xor(v, 4);
            v += __shfl_xor(v, 8);
            s[mf][r] = v;
        }
    }
    if (r16 == 0) {
        #pragma unroll
        for (int mf = 0; mf < 4; ++mf)
            #pragma unroll
            for (int r = 0; r < 4; ++r)
                atomicAdd(&out[mwave + mf * 16 + kb * 4 + r], s[mf][r]);
    }
}

// ---------------- fallback (round-1 VALU path) if ws too small ----------------
constexpr int BM = 64, BN = 64, BK = 32;
constexpr int FB_KSPLIT = 8, FB_KCHUNK = D / FB_KSPLIT;

__global__ __launch_bounds__(256) void opl_init(float* __restrict__ out,
                                                const float* __restrict__ bias) {
    out[threadIdx.x] = bias[0];
}

__global__ __launch_bounds__(256, 2) void opl_fused(
    const float* __restrict__ cf, const float* __restrict__ pf,
    const float* __restrict__ W, float* __restrict__ out)
{
    const int bid = blockIdx.x;
    const int mt = bid & 3;
    const int nt = (bid >> 2) & 15;
    const int kc = bid >> 6;
    const int mbase = mt * BM, nbase = nt * BN, kbase = kc * FB_KCHUNK;

    __shared__ float sW[BK][BN];
    __shared__ float sC[BK][BM + 4];

    const int tid = threadIdx.x;
    const int tx = tid & 15;
    const int ty = tid >> 4;
    const int wr = tid >> 4;
    const int wc = (tid & 15) * 4;
    const int cb = tid >> 3;
    const int ci = (tid & 7) * 4;

    float accG[4][4] = {{0.f}};
    float accH[4][4] = {{0.f}};

    for (int k0 = 0; k0 < FB_KCHUNK; k0 += BK) {
        const int kg = kbase + k0;
        const float4 w0 = *reinterpret_cast<const float4*>(&W[(size_t)(kg + wr) * D + nbase + wc]);
        const float4 w1 = *reinterpret_cast<const float4*>(&W[(size_t)(kg + wr + 16) * D + nbase + wc]);
        const float4 c0 = *reinterpret_cast<const float4*>(&cf[(size_t)(mbase + cb) * D + kg + ci]);
        const float4 c1 = *reinterpret_cast<const float4*>(&cf[(size_t)(mbase + cb + 32) * D + kg + ci]);
        *reinterpret_cast<float4*>(&sW[wr][wc]) = w0;
        *reinterpret_cast<float4*>(&sW[wr + 16][wc]) = w1;
        sC[ci + 0][cb] = c0.x; sC[ci + 1][cb] = c0.y;
        sC[ci + 2][cb] = c0.z; sC[ci + 3][cb] = c0.w;
        sC[ci + 0][cb + 32] = c1.x; sC[ci + 1][cb + 32] = c1.y;
        sC[ci + 2][cb + 32] = c1.z; sC[ci + 3][cb + 32] = c1.w;
        __syncthreads();
        #pragma unroll
        for (int k = 0; k < BK; ++k) {
            const float4 wv = *reinterpret_cast<const float4*>(&sW[k][tx * 4]);
            const float4 cv = *reinterpret_cast<const float4*>(&sC[k][ty * 4]);
            const float w[4] = {wv.x, wv.y, wv.z, wv.w};
            const float c[4] = {cv.x, cv.y, cv.z, cv.w};
            #pragma unroll
            for (int r = 0; r < 4; ++r) {
                const float cc = c[r];
                const float aa = fabsf(cc);
                #pragma unroll
                for (int q = 0; q < 4; ++q) {
                    accG[r][q] = fmaf(cc, w[q], accG[r][q]);
                    accH[r][q] = fmaf(aa, w[q], accH[r][q]);
                }
            }
        }
        __syncthreads();
    }
    float s[4];
    #pragma unroll
    for (int r = 0; r < 4; ++r) {
        const int b = mbase + ty * 4 + r;
        const float4 pv = *reinterpret_cast<const float4*>(&pf[(size_t)b * D + nbase + tx * 4]);
        const float p[4] = {pv.x, pv.y, pv.z, pv.w};
        float acc = 0.f;
        #pragma unroll
        for (int q = 0; q < 4; ++q)
            acc += 0.55f * p[q] * accG[r][q] + 0.45f * fabsf(p[q]) * accH[r][q];
        s[r] = acc;
    }
    #pragma unroll
    for (int r = 0; r < 4; ++r) {
        s[r] += __shfl_xor(s[r], 1);
        s[r] += __shfl_xor(s[r], 2);
        s[r] += __shfl_xor(s[r], 4);
        s[r] += __shfl_xor(s[r], 8);
    }
    if (tx == 0) {
        #pragma unroll
        for (int r = 0; r < 4; ++r)
            atomicAdd(&out[mbase + ty * 4 + r], s[r]);
    }
}

extern "C" void kernel_launch(void* const* d_in, const int* in_sizes, int n_in,
                              void* d_out, int out_size, void* d_ws, size_t ws_size,
                              hipStream_t stream) {
    const float* cf   = (const float*)d_in[0];
    const float* pf   = (const float*)d_in[1];
    const float* W    = (const float*)d_in[2];
    const float* bias = (const float*)d_in[3];
    float* out = (float*)d_out;

    const size_t wt_bytes = (size_t)D * D * sizeof(ushort);   // 2 MB
    const size_t cf_bytes = (size_t)B * D * sizeof(ushort);   // 512 KB

    if (ws_size >= wt_bytes + cf_bytes) {
        ushort* Wt  = (ushort*)d_ws;
        ushort* cfb = (ushort*)((char*)d_ws + wt_bytes);
        opl_prep<<<385, 256, 0, stream>>>(W, cf, bias, Wt, cfb, out);
        opl_mfma<<<NTILES * KSPLIT, 256, 0, stream>>>(cfb, Wt, pf, out);
    } else {
        opl_init<<<1, 256, 0, stream>>>(out, bias);
        opl_fused<<<(B / BM) * (D / BN) * FB_KSPLIT, 256, 0, stream>>>(cf, pf, W, out);
    }
}